// Round 1
// baseline (158.676 us; speedup 1.0000x reference)
//
#include <hip/hip_runtime.h>
#include <hip/hip_bf16.h>

#define D_IN  1024
#define D_H   512
#define L2E2  2.885390081777927f   // 2*log2(e)

// ---------------------------------------------------------------------------
// proj: C[i][j] = (V[i,:] . Wrow_j + bias_j) * 2*log2(e)
//   j in [0,512)    : Wrow_j = W_h[j],     bias = b_h[j]
//   j in [512,1024) : Wrow_j = W_m[j-512], bias = b_m[j-512]
// C is [1024][1024] fp32 in workspace. 64x64 tile, 256 thr, 4x4/thread.
// ---------------------------------------------------------------------------
__global__ __launch_bounds__(256) void proj_kernel(
    const float* __restrict__ V,
    const float* __restrict__ Wh, const float* __restrict__ bh,
    const float* __restrict__ Wm, const float* __restrict__ bm,
    float* __restrict__ C)
{
  __shared__ float As[16][68];   // [kk][row-in-tile], pad 68 (bank spread, 16B-aligned rows)
  __shared__ float Bs[16][68];

  const int tid = threadIdx.x;
  const int bi  = blockIdx.x & 15;
  const int bj  = blockIdx.x >> 4;
  const int i0  = bi * 64, j0 = bj * 64;
  const int ti  = tid >> 4, tj = tid & 15;   // 16x16 thread grid, 4x4 outputs each
  const int sr  = tid >> 2;                  // staging row 0..63
  const int sk  = (tid & 3) << 2;            // staging k 0,4,8,12

  // whole block is on one side of the h/m split (j0 multiple of 64)
  const float* Wbase = (j0 < D_H) ? (Wh + (size_t)j0 * D_IN)
                                  : (Wm + (size_t)(j0 - D_H) * D_IN);
  const float* biasp = (j0 < D_H) ? (bh + j0) : (bm + (j0 - D_H));

  const float* arow = V     + (size_t)(i0 + sr) * D_IN + sk;
  const float* brow = Wbase + (size_t)sr        * D_IN + sk;

  float acc[4][4] = {};
  for (int k0 = 0; k0 < D_IN; k0 += 16) {
    float4 av = *(const float4*)(arow + k0);
    float4 bv = *(const float4*)(brow + k0);
    As[sk+0][sr] = av.x; As[sk+1][sr] = av.y; As[sk+2][sr] = av.z; As[sk+3][sr] = av.w;
    Bs[sk+0][sr] = bv.x; Bs[sk+1][sr] = bv.y; Bs[sk+2][sr] = bv.z; Bs[sk+3][sr] = bv.w;
    __syncthreads();
    #pragma unroll
    for (int kk = 0; kk < 16; ++kk) {
      float4 a = *(const float4*)&As[kk][4*ti];
      float4 b = *(const float4*)&Bs[kk][4*tj];
      acc[0][0] = fmaf(a.x, b.x, acc[0][0]);
      acc[0][1] = fmaf(a.x, b.y, acc[0][1]);
      acc[0][2] = fmaf(a.x, b.z, acc[0][2]);
      acc[0][3] = fmaf(a.x, b.w, acc[0][3]);
      acc[1][0] = fmaf(a.y, b.x, acc[1][0]);
      acc[1][1] = fmaf(a.y, b.y, acc[1][1]);
      acc[1][2] = fmaf(a.y, b.z, acc[1][2]);
      acc[1][3] = fmaf(a.y, b.w, acc[1][3]);
      acc[2][0] = fmaf(a.z, b.x, acc[2][0]);
      acc[2][1] = fmaf(a.z, b.y, acc[2][1]);
      acc[2][2] = fmaf(a.z, b.z, acc[2][2]);
      acc[2][3] = fmaf(a.z, b.w, acc[2][3]);
      acc[3][0] = fmaf(a.w, b.x, acc[3][0]);
      acc[3][1] = fmaf(a.w, b.y, acc[3][1]);
      acc[3][2] = fmaf(a.w, b.z, acc[3][2]);
      acc[3][3] = fmaf(a.w, b.w, acc[3][3]);
    }
    __syncthreads();
  }

  const int jl = 4 * tj;
  #pragma unroll
  for (int aa = 0; aa < 4; ++aa) {
    const int i = i0 + 4*ti + aa;
    float4 o;
    o.x = (acc[aa][0] + biasp[jl+0]) * L2E2;
    o.y = (acc[aa][1] + biasp[jl+1]) * L2E2;
    o.z = (acc[aa][2] + biasp[jl+2]) * L2E2;
    o.w = (acc[aa][3] + biasp[jl+3]) * L2E2;
    *(float4*)(C + (size_t)i * 1024 + j0 + jl) = o;
  }
}

// ---------------------------------------------------------------------------
// score: out[i][j] = b2 + sum(w2) - 2 * sum_k w2[k] * rcp(exp2(hs[i,k]+ms[j,k]) + 1)
// where hs/ms are the pre-scaled (2*log2e) projections living in C.
// 32x32 tile/block, 256 thr, 2x2/thread, KC=32 LDS chunks.
// ---------------------------------------------------------------------------
__global__ __launch_bounds__(256) void score_kernel(
    const float* __restrict__ C,
    const float* __restrict__ w2,
    const float* __restrict__ b2,
    float* __restrict__ out)
{
  __shared__ float hs[32][34];   // [kk][row], pad 34 -> conflict-free b64 reads
  __shared__ float ms[32][34];
  __shared__ float w2s[D_H];
  __shared__ float wred[4];

  const int tid = threadIdx.x;
  const int bi  = blockIdx.x & 31;
  const int bj  = blockIdx.x >> 5;
  const int i0  = bi * 32, j0 = bj * 32;
  const int ti  = tid >> 4, tj = tid & 15;  // 16x16 threads, 2x2 outputs each
  const int sr  = tid >> 3;                 // staging row 0..31
  const int sk  = (tid & 7) << 2;           // staging k 0..28 step 4

  // stage w2 once; block-reduce sum(w2)
  float sw = 0.f;
  for (int t = tid; t < D_H; t += 256) { float w = w2[t]; w2s[t] = w; sw += w; }
  #pragma unroll
  for (int off = 32; off > 0; off >>= 1) sw += __shfl_down(sw, off, 64);
  if ((tid & 63) == 0) wred[tid >> 6] = sw;

  const float* hrow = C + (size_t)(i0 + sr) * 1024 + sk;         // hs part: cols [0,512)
  const float* mrow = C + (size_t)(j0 + sr) * 1024 + D_H + sk;   // ms part: cols [512,1024)

  float a00 = 0.f, a01 = 0.f, a10 = 0.f, a11 = 0.f;
  for (int k0 = 0; k0 < D_H; k0 += 32) {
    if (k0) __syncthreads();   // protect LDS overwrite vs previous compute
    float4 hv = *(const float4*)(hrow + k0);
    float4 mv = *(const float4*)(mrow + k0);
    hs[sk+0][sr] = hv.x; hs[sk+1][sr] = hv.y; hs[sk+2][sr] = hv.z; hs[sk+3][sr] = hv.w;
    ms[sk+0][sr] = mv.x; ms[sk+1][sr] = mv.y; ms[sk+2][sr] = mv.z; ms[sk+3][sr] = mv.w;
    __syncthreads();           // also covers w2s/wred on first iteration
    #pragma unroll 8
    for (int kk = 0; kk < 32; ++kk) {
      float2 ha = *(const float2*)&hs[kk][2*ti];
      float2 mb = *(const float2*)&ms[kk][2*tj];
      float w = w2s[k0 + kk];
      float s00 = ha.x + mb.x, s01 = ha.x + mb.y;
      float s10 = ha.y + mb.x, s11 = ha.y + mb.y;
      float r00 = __builtin_amdgcn_rcpf(__builtin_amdgcn_exp2f(s00) + 1.f);
      float r01 = __builtin_amdgcn_rcpf(__builtin_amdgcn_exp2f(s01) + 1.f);
      float r10 = __builtin_amdgcn_rcpf(__builtin_amdgcn_exp2f(s10) + 1.f);
      float r11 = __builtin_amdgcn_rcpf(__builtin_amdgcn_exp2f(s11) + 1.f);
      a00 = fmaf(w, r00, a00); a01 = fmaf(w, r01, a01);
      a10 = fmaf(w, r10, a10); a11 = fmaf(w, r11, a11);
    }
  }

  const float base = b2[0] + wred[0] + wred[1] + wred[2] + wred[3];
  const int i = i0 + 2*ti, j = j0 + 2*tj;
  float2 r0, r1;
  r0.x = fmaf(-2.f, a00, base); r0.y = fmaf(-2.f, a01, base);
  r1.x = fmaf(-2.f, a10, base); r1.y = fmaf(-2.f, a11, base);
  *(float2*)(out + (size_t)i       * 1024 + j) = r0;
  *(float2*)(out + (size_t)(i + 1) * 1024 + j) = r1;
}

extern "C" void kernel_launch(void* const* d_in, const int* in_sizes, int n_in,
                              void* d_out, int out_size, void* d_ws, size_t ws_size,
                              hipStream_t stream) {
  const float* V  = (const float*)d_in[0];
  const float* Wh = (const float*)d_in[1];
  const float* bh = (const float*)d_in[2];
  const float* Wm = (const float*)d_in[3];
  const float* bm = (const float*)d_in[4];
  const float* w2 = (const float*)d_in[5];
  const float* b2 = (const float*)d_in[6];
  float* outp = (float*)d_out;
  float* C    = (float*)d_ws;   // 1024*1024 fp32 = 4 MB scratch

  proj_kernel<<<dim3(256), dim3(256), 0, stream>>>(V, Wh, bh, Wm, bm, C);
  score_kernel<<<dim3(1024), dim3(256), 0, stream>>>(C, w2, b2, outp);
}

// Round 2
// 119.943 us; speedup vs baseline: 1.3229x; 1.3229x over previous
//
#include <hip/hip_runtime.h>
#include <hip/hip_bf16.h>

#define D_IN  1024
#define D_H   512
#define L2E2  2.885390081777927f   // 2*log2(e)

// ---------------------------------------------------------------------------
// proj: C[i][j] = exp2( clamp( (V[i,:].Wrow_j + bias_j) * 2*log2(e), ±63 ) )
//   j in [0,512)    : Wrow_j = W_h[j],     bias = b_h[j]   -> Eh
//   j in [512,1024) : Wrow_j = W_m[j-512], bias = b_m[j-512]-> Em
// so that Eh[i,k]*Em[j,k] = e^{2*(h_i_k + m_j_k)}.
// C is [1024][1024] fp32 in workspace. 64x64 tile, 256 thr, 4x4/thread.
// ---------------------------------------------------------------------------
__global__ __launch_bounds__(256) void proj_kernel(
    const float* __restrict__ V,
    const float* __restrict__ Wh, const float* __restrict__ bh,
    const float* __restrict__ Wm, const float* __restrict__ bm,
    float* __restrict__ C)
{
  __shared__ float As[16][68];   // [kk][row-in-tile]
  __shared__ float Bs[16][68];

  const int tid = threadIdx.x;
  const int bi  = blockIdx.x & 15;
  const int bj  = blockIdx.x >> 4;
  const int i0  = bi * 64, j0 = bj * 64;
  const int ti  = tid >> 4, tj = tid & 15;   // 16x16 thread grid, 4x4 outputs each
  const int sr  = tid >> 2;                  // staging row 0..63
  const int sk  = (tid & 3) << 2;            // staging k 0,4,8,12

  const float* Wbase = (j0 < D_H) ? (Wh + (size_t)j0 * D_IN)
                                  : (Wm + (size_t)(j0 - D_H) * D_IN);
  const float* biasp = (j0 < D_H) ? (bh + j0) : (bm + (j0 - D_H));

  const float* arow = V     + (size_t)(i0 + sr) * D_IN + sk;
  const float* brow = Wbase + (size_t)sr        * D_IN + sk;

  float acc[4][4] = {};
  for (int k0 = 0; k0 < D_IN; k0 += 16) {
    float4 av = *(const float4*)(arow + k0);
    float4 bv = *(const float4*)(brow + k0);
    As[sk+0][sr] = av.x; As[sk+1][sr] = av.y; As[sk+2][sr] = av.z; As[sk+3][sr] = av.w;
    Bs[sk+0][sr] = bv.x; Bs[sk+1][sr] = bv.y; Bs[sk+2][sr] = bv.z; Bs[sk+3][sr] = bv.w;
    __syncthreads();
    #pragma unroll
    for (int kk = 0; kk < 16; ++kk) {
      float4 a = *(const float4*)&As[kk][4*ti];
      float4 b = *(const float4*)&Bs[kk][4*tj];
      acc[0][0] = fmaf(a.x, b.x, acc[0][0]);
      acc[0][1] = fmaf(a.x, b.y, acc[0][1]);
      acc[0][2] = fmaf(a.x, b.z, acc[0][2]);
      acc[0][3] = fmaf(a.x, b.w, acc[0][3]);
      acc[1][0] = fmaf(a.y, b.x, acc[1][0]);
      acc[1][1] = fmaf(a.y, b.y, acc[1][1]);
      acc[1][2] = fmaf(a.y, b.z, acc[1][2]);
      acc[1][3] = fmaf(a.y, b.w, acc[1][3]);
      acc[2][0] = fmaf(a.z, b.x, acc[2][0]);
      acc[2][1] = fmaf(a.z, b.y, acc[2][1]);
      acc[2][2] = fmaf(a.z, b.z, acc[2][2]);
      acc[2][3] = fmaf(a.z, b.w, acc[2][3]);
      acc[3][0] = fmaf(a.w, b.x, acc[3][0]);
      acc[3][1] = fmaf(a.w, b.y, acc[3][1]);
      acc[3][2] = fmaf(a.w, b.z, acc[3][2]);
      acc[3][3] = fmaf(a.w, b.w, acc[3][3]);
    }
    __syncthreads();
  }

  const int jl = 4 * tj;
  #pragma unroll
  for (int aa = 0; aa < 4; ++aa) {
    const int i = i0 + 4*ti + aa;
    float4 o;
    #pragma unroll
    for (int bb = 0; bb < 4; ++bb) {
      float x = (acc[aa][bb] + biasp[jl+bb]) * L2E2;
      x = fminf(fmaxf(x, -63.f), 63.f);          // v_med3; keeps Eh*Em finite
      (&o.x)[bb] = __builtin_amdgcn_exp2f(x);
    }
    *(float4*)(C + (size_t)i * 1024 + j0 + jl) = o;
  }
}

// ---------------------------------------------------------------------------
// score: out[i][j] = b2 + sum(w2) - 2 * sum_k w2[k] * rcp(fma(Eh[i,k],Em[j,k],1))
// 64x32 tile/block (i x j), 256 thr, 4x2/thread, KC=32 LDS chunks.
// ---------------------------------------------------------------------------
__global__ __launch_bounds__(256) void score_kernel(
    const float* __restrict__ C,
    const float* __restrict__ w2,
    const float* __restrict__ b2,
    float* __restrict__ out)
{
  __shared__ float hs[32][68];   // [kk][row 0..63], stride 68 -> 16B-aligned rows
  __shared__ float ms[32][36];   // [kk][row 0..31]
  __shared__ float w2s[D_H];
  __shared__ float wred[4];

  const int tid = threadIdx.x;
  const int bi  = blockIdx.x & 15;   // 16 i-tiles of 64
  const int bj  = blockIdx.x >> 4;   // 32 j-tiles of 32
  const int i0  = bi * 64, j0 = bj * 32;
  const int ti  = tid >> 4, tj = tid & 15;  // 16x16 threads; 4 rows x 2 cols each

  // staging maps
  const int hrA = tid >> 2;                 // h row 0..63
  const int hkA = (tid & 3) << 2;           // h k 0,4,8,12 (+16 for 2nd load)
  const int mrB = tid >> 3;                 // m row 0..31
  const int mkB = (tid & 7) << 2;           // m k 0..28

  // stage w2 once; block-reduce sum(w2)
  float sw = 0.f;
  for (int t = tid; t < D_H; t += 256) { float w = w2[t]; w2s[t] = w; sw += w; }
  #pragma unroll
  for (int off = 32; off > 0; off >>= 1) sw += __shfl_down(sw, off, 64);
  if ((tid & 63) == 0) wred[tid >> 6] = sw;

  const float* hrow = C + (size_t)(i0 + hrA) * 1024 + hkA;         // Eh: cols [0,512)
  const float* mrow = C + (size_t)(j0 + mrB) * 1024 + D_H + mkB;   // Em: cols [512,1024)

  float acc[4][2] = {};
  for (int k0 = 0; k0 < D_H; k0 += 32) {
    if (k0) __syncthreads();
    float4 hv1 = *(const float4*)(hrow + k0);
    float4 hv2 = *(const float4*)(hrow + k0 + 16);
    float4 mv  = *(const float4*)(mrow + k0);
    hs[hkA+0][hrA] = hv1.x; hs[hkA+1][hrA] = hv1.y; hs[hkA+2][hrA] = hv1.z; hs[hkA+3][hrA] = hv1.w;
    hs[hkA+16][hrA] = hv2.x; hs[hkA+17][hrA] = hv2.y; hs[hkA+18][hrA] = hv2.z; hs[hkA+19][hrA] = hv2.w;
    ms[mkB+0][mrB] = mv.x; ms[mkB+1][mrB] = mv.y; ms[mkB+2][mrB] = mv.z; ms[mkB+3][mrB] = mv.w;
    __syncthreads();           // also covers w2s/wred on first iteration
    #pragma unroll
    for (int kk = 0; kk < 32; ++kk) {
      float4 ha = *(const float4*)&hs[kk][4*ti];
      float2 mb = *(const float2*)&ms[kk][2*tj];
      float w = w2s[k0 + kk];
      #pragma unroll
      for (int r = 0; r < 4; ++r) {
        float d0 = fmaf((&ha.x)[r], mb.x, 1.f);
        float d1 = fmaf((&ha.x)[r], mb.y, 1.f);
        float r0 = __builtin_amdgcn_rcpf(d0);
        float r1 = __builtin_amdgcn_rcpf(d1);
        acc[r][0] = fmaf(w, r0, acc[r][0]);
        acc[r][1] = fmaf(w, r1, acc[r][1]);
      }
    }
  }

  const float base = b2[0] + wred[0] + wred[1] + wred[2] + wred[3];
  const int j = j0 + 2*tj;
  #pragma unroll
  for (int r = 0; r < 4; ++r) {
    const int i = i0 + 4*ti + r;
    float2 o;
    o.x = fmaf(-2.f, acc[r][0], base);
    o.y = fmaf(-2.f, acc[r][1], base);
    *(float2*)(out + (size_t)i * 1024 + j) = o;
  }
}

extern "C" void kernel_launch(void* const* d_in, const int* in_sizes, int n_in,
                              void* d_out, int out_size, void* d_ws, size_t ws_size,
                              hipStream_t stream) {
  const float* V  = (const float*)d_in[0];
  const float* Wh = (const float*)d_in[1];
  const float* bh = (const float*)d_in[2];
  const float* Wm = (const float*)d_in[3];
  const float* bm = (const float*)d_in[4];
  const float* w2 = (const float*)d_in[5];
  const float* b2 = (const float*)d_in[6];
  float* outp = (float*)d_out;
  float* C    = (float*)d_ws;   // 1024*1024 fp32 = 4 MB scratch

  proj_kernel<<<dim3(256), dim3(256), 0, stream>>>(V, Wh, bh, Wm, bm, C);
  score_kernel<<<dim3(512), dim3(256), 0, stream>>>(C, w2, b2, outp);
}

// Round 3
// 115.059 us; speedup vs baseline: 1.3791x; 1.0424x over previous
//
#include <hip/hip_runtime.h>
#include <hip/hip_bf16.h>

#define D_IN  1024
#define D_H   512
#define L2E2  2.885390081777927f   // 2*log2(e)
#define ECLAMP 15.0f               // exp2-arg clamp: e in [2^-15, 2^15]

typedef float v2f __attribute__((ext_vector_type(2)));
static __device__ __forceinline__ v2f pkfma(v2f a, v2f b, v2f c) {
  return __builtin_elementwise_fma(a, b, c);
}

// ---------------------------------------------------------------------------
// proj: C[i][j] = exp2( clamp( (V[i,:].Wrow_j + bias_j) * 2*log2(e), +-15 ) )
//   j in [0,512)    : W_h row -> Eh ;  j in [512,1024) : W_m row -> Em
// Eh[i,k]*Em[j,k] = e^{2*(h+m)};  tanh = 1 - 2/(1+e).
// ---------------------------------------------------------------------------
__global__ __launch_bounds__(256) void proj_kernel(
    const float* __restrict__ V,
    const float* __restrict__ Wh, const float* __restrict__ bh,
    const float* __restrict__ Wm, const float* __restrict__ bm,
    float* __restrict__ C)
{
  __shared__ float As[16][68];
  __shared__ float Bs[16][68];

  const int tid = threadIdx.x;
  const int bi  = blockIdx.x & 15;
  const int bj  = blockIdx.x >> 4;
  const int i0  = bi * 64, j0 = bj * 64;
  const int ti  = tid >> 4, tj = tid & 15;
  const int sr  = tid >> 2;
  const int sk  = (tid & 3) << 2;

  const float* Wbase = (j0 < D_H) ? (Wh + (size_t)j0 * D_IN)
                                  : (Wm + (size_t)(j0 - D_H) * D_IN);
  const float* biasp = (j0 < D_H) ? (bh + j0) : (bm + (j0 - D_H));

  const float* arow = V     + (size_t)(i0 + sr) * D_IN + sk;
  const float* brow = Wbase + (size_t)sr        * D_IN + sk;

  float acc[4][4] = {};
  for (int k0 = 0; k0 < D_IN; k0 += 16) {
    float4 av = *(const float4*)(arow + k0);
    float4 bv = *(const float4*)(brow + k0);
    As[sk+0][sr] = av.x; As[sk+1][sr] = av.y; As[sk+2][sr] = av.z; As[sk+3][sr] = av.w;
    Bs[sk+0][sr] = bv.x; Bs[sk+1][sr] = bv.y; Bs[sk+2][sr] = bv.z; Bs[sk+3][sr] = bv.w;
    __syncthreads();
    #pragma unroll
    for (int kk = 0; kk < 16; ++kk) {
      float4 a = *(const float4*)&As[kk][4*ti];
      float4 b = *(const float4*)&Bs[kk][4*tj];
      #pragma unroll
      for (int x = 0; x < 4; ++x)
        #pragma unroll
        for (int y = 0; y < 4; ++y)
          acc[x][y] = fmaf((&a.x)[x], (&b.x)[y], acc[x][y]);
    }
    __syncthreads();
  }

  const int jl = 4 * tj;
  #pragma unroll
  for (int aa = 0; aa < 4; ++aa) {
    const int i = i0 + 4*ti + aa;
    float4 o;
    #pragma unroll
    for (int bb = 0; bb < 4; ++bb) {
      float x = (acc[aa][bb] + biasp[jl+bb]) * L2E2;
      x = fminf(fmaxf(x, -ECLAMP), ECLAMP);
      (&o.x)[bb] = __builtin_amdgcn_exp2f(x);
    }
    *(float4*)(C + (size_t)i * 1024 + j0 + jl) = o;
  }
}

// ---------------------------------------------------------------------------
// score: out[i][j] = b2 + sum(w2) - 2 * sum_k w2[k]/(1 + Eh[i,k]*Em[j,k])
// 4-way k-folding: one rcp per 4 k-terms, packed fp32 over 2 j-cols.
// 64x32 tile/block, 256 thr, 4x2/thread, KC=32 LDS chunks.
// ---------------------------------------------------------------------------
__global__ __launch_bounds__(256) void score_kernel(
    const float* __restrict__ C,
    const float* __restrict__ w2,
    const float* __restrict__ b2,
    float* __restrict__ out)
{
  __shared__ float hs[32][68];   // [kk][row 0..63]
  __shared__ float ms[32][36];   // [kk][row 0..31]
  __shared__ float wred[4];

  const int tid = threadIdx.x;
  const int bi  = blockIdx.x & 15;
  const int bj  = blockIdx.x >> 4;
  const int i0  = bi * 64, j0 = bj * 32;
  const int ti  = tid >> 4, tj = tid & 15;

  const int hrA = tid >> 2;
  const int hkA = (tid & 3) << 2;
  const int mrB = tid >> 3;
  const int mkB = (tid & 7) << 2;

  // block-reduce sum(w2)
  float sw = 0.f;
  for (int t = tid; t < D_H; t += 256) sw += w2[t];
  #pragma unroll
  for (int off = 32; off > 0; off >>= 1) sw += __shfl_down(sw, off, 64);
  if ((tid & 63) == 0) wred[tid >> 6] = sw;

  const float* hrow = C + (size_t)(i0 + hrA) * 1024 + hkA;         // Eh cols [0,512)
  const float* mrow = C + (size_t)(j0 + mrB) * 1024 + D_H + mkB;   // Em cols [512,1024)

  v2f acc[4] = {v2f{0.f,0.f}, v2f{0.f,0.f}, v2f{0.f,0.f}, v2f{0.f,0.f}};

  for (int k0 = 0; k0 < D_H; k0 += 32) {
    if (k0) __syncthreads();
    float4 hv1 = *(const float4*)(hrow + k0);
    float4 hv2 = *(const float4*)(hrow + k0 + 16);
    float4 mv  = *(const float4*)(mrow + k0);
    hs[hkA+0][hrA] = hv1.x; hs[hkA+1][hrA] = hv1.y; hs[hkA+2][hrA] = hv1.z; hs[hkA+3][hrA] = hv1.w;
    hs[hkA+16][hrA] = hv2.x; hs[hkA+17][hrA] = hv2.y; hs[hkA+18][hrA] = hv2.z; hs[hkA+19][hrA] = hv2.w;
    ms[mkB+0][mrB] = mv.x; ms[mkB+1][mrB] = mv.y; ms[mkB+2][mrB] = mv.z; ms[mkB+3][mrB] = mv.w;
    __syncthreads();           // also covers wred on first iteration

    #pragma unroll
    for (int g = 0; g < 8; ++g) {          // 8 groups of 4 k each
      const int kk = 4 * g;
      // uniform scalar weights (s_load from global)
      const float wA = w2[k0 + kk + 0];
      const float wB = w2[k0 + kk + 1];
      const float wC = w2[k0 + kk + 2];
      const float wD = w2[k0 + kk + 3];
      const v2f wAv = {wA, wA}, wBv = {wB, wB}, wCv = {wC, wC}, wDv = {wD, wD};
      const v2f w01 = {wA + wB, wA + wB};
      const v2f w23 = {wC + wD, wC + wD};

      v2f emA = *(const v2f*)&ms[kk+0][2*tj];
      v2f emB = *(const v2f*)&ms[kk+1][2*tj];
      v2f emC = *(const v2f*)&ms[kk+2][2*tj];
      v2f emD = *(const v2f*)&ms[kk+3][2*tj];
      float4 ehA = *(const float4*)&hs[kk+0][4*ti];
      float4 ehB = *(const float4*)&hs[kk+1][4*ti];
      float4 ehC = *(const float4*)&hs[kk+2][4*ti];
      float4 ehD = *(const float4*)&hs[kk+3][4*ti];

      #pragma unroll
      for (int r = 0; r < 4; ++r) {
        v2f a = emA * (&ehA.x)[r];
        v2f b = emB * (&ehB.x)[r];
        v2f c = emC * (&ehC.x)[r];
        v2f d = emD * (&ehD.x)[r];
        // pair (a,b): den = (1+a)(1+b), num = wA(1+b)+wB(1+a)
        v2f uA   = a + 1.f;
        v2f denA = pkfma(uA, b, uA);
        v2f tA   = pkfma(wAv, b, w01);
        v2f numA = pkfma(wBv, a, tA);
        // pair (c,d)
        v2f uC   = c + 1.f;
        v2f denC = pkfma(uC, d, uC);
        v2f tC   = pkfma(wCv, d, w23);
        v2f numC = pkfma(wDv, c, tC);
        // combine
        v2f m2  = numA * denC;
        v2f num = pkfma(numC, denA, m2);
        v2f den = denA * denC;
        v2f rv;
        rv.x = __builtin_amdgcn_rcpf(den.x);
        rv.y = __builtin_amdgcn_rcpf(den.y);
        acc[r] = pkfma(num, rv, acc[r]);
      }
    }
  }

  const float base = b2[0] + wred[0] + wred[1] + wred[2] + wred[3];
  const v2f basev = {base, base};
  const v2f m2v   = {-2.f, -2.f};
  const int j = j0 + 2*tj;
  #pragma unroll
  for (int r = 0; r < 4; ++r) {
    const int i = i0 + 4*ti + r;
    v2f o = pkfma(m2v, acc[r], basev);
    *(v2f*)(out + (size_t)i * 1024 + j) = o;
  }
}

extern "C" void kernel_launch(void* const* d_in, const int* in_sizes, int n_in,
                              void* d_out, int out_size, void* d_ws, size_t ws_size,
                              hipStream_t stream) {
  const float* V  = (const float*)d_in[0];
  const float* Wh = (const float*)d_in[1];
  const float* bh = (const float*)d_in[2];
  const float* Wm = (const float*)d_in[3];
  const float* bm = (const float*)d_in[4];
  const float* w2 = (const float*)d_in[5];
  const float* b2 = (const float*)d_in[6];
  float* outp = (float*)d_out;
  float* C    = (float*)d_ws;   // 1024*1024 fp32 = 4 MB scratch

  proj_kernel<<<dim3(256), dim3(256), 0, stream>>>(V, Wh, bh, Wm, bm, C);
  score_kernel<<<dim3(512), dim3(256), 0, stream>>>(C, w2, b2, outp);
}

// Round 4
// 86.230 us; speedup vs baseline: 1.8401x; 1.3343x over previous
//
#include <hip/hip_runtime.h>
#include <hip/hip_bf16.h>

#define D_IN  1024
#define D_H   512
#define L2E2  2.885390081777927f   // 2*log2(e)
#define ECLAMP 15.0f               // exp2-arg clamp: e in [2^-15, 2^15]

typedef _Float16 half8 __attribute__((ext_vector_type(8)));
typedef _Float16 half4v __attribute__((ext_vector_type(4)));
typedef float f32x4 __attribute__((ext_vector_type(4)));

// ---------------------------------------------------------------------------
// cvt: V (1024x1024 f32) -> Vh f16 ; [Wh;Wm] (1024x1024 f32) -> Wf f16
// 262144 threads, one float4 of V and one of W each.
// ---------------------------------------------------------------------------
__global__ __launch_bounds__(256) void cvt_kernel(
    const float* __restrict__ V,
    const float* __restrict__ Wh, const float* __restrict__ Wm,
    _Float16* __restrict__ Vh, _Float16* __restrict__ Wf)
{
  const int idx = blockIdx.x * 256 + threadIdx.x;   // 0..262143 float4s
  {
    float4 x = ((const float4*)V)[idx];
    half4v o = { (_Float16)x.x, (_Float16)x.y, (_Float16)x.z, (_Float16)x.w };
    ((half4v*)Vh)[idx] = o;
  }
  {
    const float4* p = (idx < 131072) ? ((const float4*)Wh + idx)
                                     : ((const float4*)Wm + (idx - 131072));
    float4 x = *p;
    half4v o = { (_Float16)x.x, (_Float16)x.y, (_Float16)x.z, (_Float16)x.w };
    ((half4v*)Wf)[idx] = o;
  }
}

// ---------------------------------------------------------------------------
// proj via MFMA: C[i][j] = exp2(clamp((V[i,:].Wrow_j + bias_j)*2log2e, +-15))
// 64x64 block tile, 4 waves (2x2), 32x32 per wave, f16 16x16x32 MFMA,
// direct global fragment loads (L2-resident data).
// ---------------------------------------------------------------------------
__global__ __launch_bounds__(256) void proj_mfma_kernel(
    const _Float16* __restrict__ Vh, const _Float16* __restrict__ Wf,
    const float* __restrict__ bh, const float* __restrict__ bm,
    float* __restrict__ C)
{
  const int tid  = threadIdx.x;
  const int lane = tid & 63;
  const int wid  = tid >> 6;          // 0..3
  const int wi   = wid >> 1, wj = wid & 1;
  const int i0   = (blockIdx.x & 15) * 64;
  const int j0   = (blockIdx.x >> 4) * 64;
  const int r16  = lane & 15;
  const int kg   = lane >> 4;         // k-group 0..3

  const _Float16* A0 = Vh + (size_t)(i0 + 32*wi + r16) * 1024 + kg*8;
  const _Float16* A1 = A0 + 16 * 1024;
  const _Float16* B0 = Wf + (size_t)(j0 + 32*wj + r16) * 1024 + kg*8;
  const _Float16* B1 = B0 + 16 * 1024;

  f32x4 acc00 = {0.f,0.f,0.f,0.f}, acc01 = acc00, acc10 = acc00, acc11 = acc00;
  #pragma unroll 4
  for (int k0 = 0; k0 < D_IN; k0 += 32) {
    half8 a0 = *(const half8*)(A0 + k0);
    half8 a1 = *(const half8*)(A1 + k0);
    half8 b0 = *(const half8*)(B0 + k0);
    half8 b1 = *(const half8*)(B1 + k0);
    acc00 = __builtin_amdgcn_mfma_f32_16x16x32_f16(a0, b0, acc00, 0, 0, 0);
    acc01 = __builtin_amdgcn_mfma_f32_16x16x32_f16(a0, b1, acc01, 0, 0, 0);
    acc10 = __builtin_amdgcn_mfma_f32_16x16x32_f16(a1, b0, acc10, 0, 0, 0);
    acc11 = __builtin_amdgcn_mfma_f32_16x16x32_f16(a1, b1, acc11, 0, 0, 0);
  }

  const float* biasp = (j0 < D_H) ? (bh + j0) : (bm + (j0 - D_H));
  // C/D layout (m89-verified): col = lane&15, row = (lane>>4)*4 + reg
  #pragma unroll
  for (int fi = 0; fi < 2; ++fi) {
    #pragma unroll
    for (int fj = 0; fj < 2; ++fj) {
      const f32x4 acc = (fi == 0) ? (fj == 0 ? acc00 : acc01)
                                  : (fj == 0 ? acc10 : acc11);
      const int jl = 32*wj + 16*fj + r16;
      const float bias = biasp[jl];
      #pragma unroll
      for (int rr = 0; rr < 4; ++rr) {
        const int il = 32*wi + 16*fi + 4*kg + rr;
        float x = (acc[rr] + bias) * L2E2;
        x = fminf(fmaxf(x, -ECLAMP), ECLAMP);
        C[(size_t)(i0 + il) * 1024 + j0 + jl] = __builtin_amdgcn_exp2f(x);
      }
    }
  }
}

// ---------------------------------------------------------------------------
// proj fallback (fp32 vector GEMM) when ws is too small for f16 staging.
// ---------------------------------------------------------------------------
__global__ __launch_bounds__(256) void proj_kernel(
    const float* __restrict__ V,
    const float* __restrict__ Wh, const float* __restrict__ bh,
    const float* __restrict__ Wm, const float* __restrict__ bm,
    float* __restrict__ C)
{
  __shared__ float As[16][68];
  __shared__ float Bs[16][68];

  const int tid = threadIdx.x;
  const int bi  = blockIdx.x & 15;
  const int bj  = blockIdx.x >> 4;
  const int i0  = bi * 64, j0 = bj * 64;
  const int ti  = tid >> 4, tj = tid & 15;
  const int sr  = tid >> 2;
  const int sk  = (tid & 3) << 2;

  const float* Wbase = (j0 < D_H) ? (Wh + (size_t)j0 * D_IN)
                                  : (Wm + (size_t)(j0 - D_H) * D_IN);
  const float* biasp = (j0 < D_H) ? (bh + j0) : (bm + (j0 - D_H));

  const float* arow = V     + (size_t)(i0 + sr) * D_IN + sk;
  const float* brow = Wbase + (size_t)sr        * D_IN + sk;

  float acc[4][4] = {};
  for (int k0 = 0; k0 < D_IN; k0 += 16) {
    float4 av = *(const float4*)(arow + k0);
    float4 bv = *(const float4*)(brow + k0);
    As[sk+0][sr] = av.x; As[sk+1][sr] = av.y; As[sk+2][sr] = av.z; As[sk+3][sr] = av.w;
    Bs[sk+0][sr] = bv.x; Bs[sk+1][sr] = bv.y; Bs[sk+2][sr] = bv.z; Bs[sk+3][sr] = bv.w;
    __syncthreads();
    #pragma unroll
    for (int kk = 0; kk < 16; ++kk) {
      float4 a = *(const float4*)&As[kk][4*ti];
      float4 b = *(const float4*)&Bs[kk][4*tj];
      #pragma unroll
      for (int x = 0; x < 4; ++x)
        #pragma unroll
        for (int y = 0; y < 4; ++y)
          acc[x][y] = fmaf((&a.x)[x], (&b.x)[y], acc[x][y]);
    }
    __syncthreads();
  }

  const int jl = 4 * tj;
  #pragma unroll
  for (int aa = 0; aa < 4; ++aa) {
    const int i = i0 + 4*ti + aa;
    float4 o;
    #pragma unroll
    for (int bb = 0; bb < 4; ++bb) {
      float x = (acc[aa][bb] + biasp[jl+bb]) * L2E2;
      x = fminf(fmaxf(x, -ECLAMP), ECLAMP);
      (&o.x)[bb] = __builtin_amdgcn_exp2f(x);
    }
    *(float4*)(C + (size_t)i * 1024 + j0 + jl) = o;
  }
}

// ---------------------------------------------------------------------------
// score: out[i][j] = b2 + sum(w2) - 2 * sum_k w2[k]/(1 + Eh[i,k]*Em[j,k])
// 32x32 tile/block (1024 blocks -> 4 blocks/CU), 2x2/thread, scalar fma,
// 4-way k-fold: u=fma(eh,em,1); one rcp per 4 k-terms per output.
// ---------------------------------------------------------------------------
__global__ __launch_bounds__(256) void score_kernel(
    const float* __restrict__ C,
    const float* __restrict__ w2,
    const float* __restrict__ b2,
    float* __restrict__ out)
{
  __shared__ float hs[32][36];
  __shared__ float ms[32][36];
  __shared__ float wred[4];

  const int tid = threadIdx.x;
  const int bi  = blockIdx.x & 31;
  const int bj  = blockIdx.x >> 5;
  const int i0  = bi * 32, j0 = bj * 32;
  const int ti  = tid >> 4, tj = tid & 15;   // 16x16 threads, 2x2 outputs
  const int sr  = tid >> 3;                  // staging row 0..31
  const int sk  = (tid & 7) << 2;            // staging k 0..28

  // block-reduce sum(w2)
  float sw = 0.f;
  for (int t = tid; t < D_H; t += 256) sw += w2[t];
  #pragma unroll
  for (int off = 32; off > 0; off >>= 1) sw += __shfl_down(sw, off, 64);
  if ((tid & 63) == 0) wred[tid >> 6] = sw;

  const float* hrow = C + (size_t)(i0 + sr) * 1024 + sk;         // Eh cols [0,512)
  const float* mrow = C + (size_t)(j0 + sr) * 1024 + D_H + sk;   // Em cols [512,1024)

  float a00 = 0.f, a01 = 0.f, a10 = 0.f, a11 = 0.f;

  for (int k0 = 0; k0 < D_H; k0 += 32) {
    if (k0) __syncthreads();
    float4 hv = *(const float4*)(hrow + k0);
    float4 mv = *(const float4*)(mrow + k0);
    *(float4*)&hs[sr][sk] = hv;
    *(float4*)&ms[sr][sk] = mv;
    __syncthreads();           // also covers wred on first iteration

    #pragma unroll
    for (int g = 0; g < 8; ++g) {
      const int kk = 4 * g;
      const float wA = w2[k0 + kk + 0];
      const float wB = w2[k0 + kk + 1];
      const float wC = w2[k0 + kk + 2];
      const float wD = w2[k0 + kk + 3];
      float4 eh0 = *(const float4*)&hs[2*ti    ][kk];
      float4 eh1 = *(const float4*)&hs[2*ti + 1][kk];
      float4 em0 = *(const float4*)&ms[2*tj    ][kk];
      float4 em1 = *(const float4*)&ms[2*tj + 1][kk];

      // per output: sum over 4 k of w/(1+eh*em), one rcp
      #define TERM(EH, EM, ACC)                                        \
      {                                                                \
        float uA = fmaf((EH).x, (EM).x, 1.f);                          \
        float uB = fmaf((EH).y, (EM).y, 1.f);                          \
        float uC = fmaf((EH).z, (EM).z, 1.f);                          \
        float uD = fmaf((EH).w, (EM).w, 1.f);                          \
        float dAB = uA * uB, dCD = uC * uD;                            \
        float nAB = fmaf(wB, uA, wA * uB);                             \
        float nCD = fmaf(wD, uC, wC * uD);                             \
        float den = dAB * dCD;                                         \
        float num = fmaf(nCD, dAB, nAB * dCD);                         \
        ACC = fmaf(num, __builtin_amdgcn_rcpf(den), ACC);              \
      }
      TERM(eh0, em0, a00)
      TERM(eh0, em1, a01)
      TERM(eh1, em0, a10)
      TERM(eh1, em1, a11)
      #undef TERM
    }
  }

  const float base = b2[0] + wred[0] + wred[1] + wred[2] + wred[3];
  const int i = i0 + 2*ti, j = j0 + 2*tj;
  float2 r0, r1;
  r0.x = fmaf(-2.f, a00, base); r0.y = fmaf(-2.f, a01, base);
  r1.x = fmaf(-2.f, a10, base); r1.y = fmaf(-2.f, a11, base);
  *(float2*)(out + (size_t)i       * 1024 + j) = r0;
  *(float2*)(out + (size_t)(i + 1) * 1024 + j) = r1;
}

extern "C" void kernel_launch(void* const* d_in, const int* in_sizes, int n_in,
                              void* d_out, int out_size, void* d_ws, size_t ws_size,
                              hipStream_t stream) {
  const float* V  = (const float*)d_in[0];
  const float* Wh = (const float*)d_in[1];
  const float* bh = (const float*)d_in[2];
  const float* Wm = (const float*)d_in[3];
  const float* bm = (const float*)d_in[4];
  const float* w2 = (const float*)d_in[5];
  const float* b2 = (const float*)d_in[6];
  float* outp = (float*)d_out;

  char* ws = (char*)d_ws;
  float* C = (float*)ws;                                 // 4 MB: Eh|Em
  if (ws_size >= (size_t)(8u << 20)) {
    _Float16* Vh = (_Float16*)(ws + (4u << 20));         // 2 MB
    _Float16* Wf = (_Float16*)(ws + (6u << 20));         // 2 MB
    cvt_kernel<<<dim3(1024), dim3(256), 0, stream>>>(V, Wh, Wm, Vh, Wf);
    proj_mfma_kernel<<<dim3(256), dim3(256), 0, stream>>>(Vh, Wf, bh, bm, C);
  } else {
    proj_kernel<<<dim3(256), dim3(256), 0, stream>>>(V, Wh, bh, Wm, bm, C);
  }
  score_kernel<<<dim3(1024), dim3(256), 0, stream>>>(C, w2, b2, outp);
}